// Round 4
// baseline (2035.149 us; speedup 1.0000x reference)
//
#include <hip/hip_runtime.h>

#define NB      16
#define NPTS    4096
#define NPOINT  1024
#define NSAMPLE 32

// ---------------- DPP / swizzle / bpermute u64-key max helpers ----------------
template <int C>
__device__ __forceinline__ int dppi(int v) {
  return __builtin_amdgcn_update_dpp(0, v, C, 0xf, 0xf, true);
}

template <int C>
__device__ __forceinline__ unsigned long long dppmax_u64(unsigned long long k) {
  int lo = dppi<C>((int)(unsigned)k);
  int hi = dppi<C>((int)(k >> 32));
  unsigned long long o = ((unsigned long long)(unsigned)hi << 32) | (unsigned)lo;
  return o > k ? o : k;
}

__device__ __forceinline__ unsigned long long swzmax16_u64(unsigned long long k) {
  int lo = __builtin_amdgcn_ds_swizzle((int)(unsigned)k, 0x401F);  // lane ^= 16
  int hi = __builtin_amdgcn_ds_swizzle((int)(k >> 32), 0x401F);
  unsigned long long o = ((unsigned long long)(unsigned)hi << 32) | (unsigned)lo;
  return o > k ? o : k;
}

__device__ __forceinline__ unsigned long long bpermmax32_u64(unsigned long long k, int addr) {
  int lo = __builtin_amdgcn_ds_bpermute(addr, (int)(unsigned)k);  // lane ^= 32
  int hi = __builtin_amdgcn_ds_bpermute(addr, (int)(k >> 32));
  unsigned long long o = ((unsigned long long)(unsigned)hi << 32) | (unsigned)lo;
  return o > k ? o : k;
}

// tuple-carrying max step (key + 3 coords follow the winner)
template <int C>
__device__ __forceinline__ void redstep(unsigned long long& k, float& x, float& y, float& z) {
  int lo = dppi<C>((int)(unsigned)k);
  int hi = dppi<C>((int)(k >> 32));
  int ox = dppi<C>(__float_as_int(x));
  int oy = dppi<C>(__float_as_int(y));
  int oz = dppi<C>(__float_as_int(z));
  unsigned long long o = ((unsigned long long)(unsigned)hi << 32) | (unsigned)lo;
  bool c = o > k;
  k = c ? o : k;
  x = c ? __int_as_float(ox) : x;
  y = c ? __int_as_float(oy) : y;
  z = c ? __int_as_float(oz) : z;
}

// 8-way mux by 3-bit selector (7 cndmask tree; static indices only)
__device__ __forceinline__ float sel8(const float* v, unsigned e) {
  const float a0 = (e & 1) ? v[1] : v[0];
  const float a1 = (e & 1) ? v[3] : v[2];
  const float a2 = (e & 1) ? v[5] : v[4];
  const float a3 = (e & 1) ? v[7] : v[6];
  const float b0 = (e & 2) ? a1 : a0;
  const float b1 = (e & 2) ? a3 : a2;
  return (e & 4) ? b1 : b0;
}

// ---------------------------------------------------------------------------
// FPS v4: 512 threads (2 waves/SIMD), 8 pts/thread. Changes vs v3:
//  - tree-shaped local argmax (depth ~8 instead of 64-cycle serial chain)
//  - winner coords CARRIED through the reduce (owner lane writes {key,x,y,z};
//    post-barrier = 4 conflict-free LDS reads + 3 tuple DPP steps). This
//    removes the 3 broadcast coord ds_reads (~120 cyc) from the serial path.
// Exact-IEEE math identical to reference; keys unique so owner is unique.
// ---------------------------------------------------------------------------
__global__ __launch_bounds__(512) void fps_kernel(const float* __restrict__ xyz,
                                                  float* __restrict__ out_xyz) {
  __shared__ float lx[NPTS], ly[NPTS], lz[NPTS];
  __shared__ unsigned long long skey[2][8];
  __shared__ float sx[2][8], sy[2][8], sz[2][8];
  const int b = blockIdx.x, t = threadIdx.x;
  const int lane = t & 63;
  const int wid = t >> 6;
  const float* g = xyz + (size_t)b * NPTS * 3;
  for (int j = t; j < NPTS; j += 512) {
    lx[j] = g[3 * j]; ly[j] = g[3 * j + 1]; lz[j] = g[3 * j + 2];
  }
  __syncthreads();
  float px[8], py[8], pz[8], mind[8];
#pragma unroll
  for (int i = 0; i < 8; ++i) {
    const int j = t + 512 * i;
    px[i] = lx[j]; py[i] = ly[j]; pz[i] = lz[j];
    mind[i] = 1e10f;
  }
  const int baddr = ((lane ^ 32) & 63) << 2;  // bpermute byte addr, loop-invariant
  float cx = lx[0], cy = ly[0], cz = lz[0];   // far = 0 initially
  float* ob = out_xyz + (size_t)b * NPOINT * 3;
  for (int it = 0; it < NPOINT; ++it) {
    if (t == 0) { ob[3 * it] = cx; ob[3 * it + 1] = cy; ob[3 * it + 2] = cz; }
    // ---- update mind (exact IEEE, no fma) ----
#pragma unroll
    for (int i = 0; i < 8; ++i) {
      const float dx = __fsub_rn(px[i], cx);
      const float dy = __fsub_rn(py[i], cy);
      const float dz = __fsub_rn(pz[i], cz);
      const float d2 = __fadd_rn(__fadd_rn(__fmul_rn(dx, dx), __fmul_rn(dy, dy)),
                                 __fmul_rn(dz, dz));
      mind[i] = fminf(mind[i], d2);
    }
    // ---- tree max + smallest-i encode (ties: smallest i == smallest j) ----
    const float m0 = fmaxf(mind[0], mind[1]), m1 = fmaxf(mind[2], mind[3]);
    const float m2 = fmaxf(mind[4], mind[5]), m3 = fmaxf(mind[6], mind[7]);
    const float m4 = fmaxf(m0, m1), m5 = fmaxf(m2, m3);
    const float m = fmaxf(m4, m5);
    unsigned e[8];
#pragma unroll
    for (int i = 0; i < 8; ++i) e[i] = (mind[i] == m) ? (unsigned)i : 255u;
    const unsigned e0 = min(e[0], e[1]), e1 = min(e[2], e[3]);
    const unsigned e2 = min(e[4], e[5]), e3 = min(e[6], e[7]);
    const unsigned enc = min(min(e0, e1), min(e2, e3));
    const unsigned aj = (unsigned)t + (enc << 9);
    const unsigned long long my =
        ((unsigned long long)__float_as_uint(m) << 32) | (unsigned)(~aj);
    // candidate coords (off critical path; overlaps butterfly)
    const float ox = sel8(px, enc), oy = sel8(py, enc), oz = sel8(pz, enc);
    // ---- in-wave butterfly on u64 key ----
    unsigned long long key = my;
    key = dppmax_u64<0xB1>(key);       // xor 1
    key = dppmax_u64<0x4E>(key);       // xor 2
    key = dppmax_u64<0x141>(key);      // half-mirror (covers 8)
    key = dppmax_u64<0x140>(key);      // mirror (covers 16)
    key = swzmax16_u64(key);           // xor 16
    key = bpermmax32_u64(key, baddr);  // xor 32 -> full-wave max
    const int buf = it & 1;
    if (my == key) {  // unique owner lane per wave
      skey[buf][wid] = key;
      sx[buf][wid] = ox; sy[buf][wid] = oy; sz[buf][wid] = oz;
    }
    __syncthreads();
    // ---- final reduce over 8 tuples (no coord lookup afterwards) ----
    const int p8 = lane & 7;
    unsigned long long rk = skey[buf][p8];
    float rx = sx[buf][p8], ry = sy[buf][p8], rz = sz[buf][p8];
    redstep<0xB1>(rk, rx, ry, rz);   // xor 1
    redstep<0x4E>(rk, rx, ry, rz);   // xor 2
    redstep<0x141>(rk, rx, ry, rz);  // covers all 8
    cx = rx; cy = ry; cz = rz;
  }
}

// ---------------------------------------------------------------------------
// Ball query: one wave per query; 64 candidates/step; ordered append via
// __ballot + prefix popcount; uniform early exit at 32 hits.
// ---------------------------------------------------------------------------
__global__ __launch_bounds__(256) void ballq_kernel(const float* __restrict__ xyz,
                                                    const float* __restrict__ new_xyz,
                                                    int* __restrict__ ballidx,
                                                    float* __restrict__ out_idx) {
  __shared__ int sidx[4][NSAMPLE];
  const int wv = threadIdx.x >> 6, lane = threadIdx.x & 63;
  const int q = blockIdx.x * 4 + wv;
  const int b = q >> 10;
  const float* g = xyz + (size_t)b * NPTS * 3;
  const float nx = new_xyz[(size_t)q * 3];
  const float ny = new_xyz[(size_t)q * 3 + 1];
  const float nz = new_xyz[(size_t)q * 3 + 2];
  const float r2 = (float)(0.2 * 0.2);  // double->f32 (NOT 0.2f*0.2f)
  int cnt = 0;
  for (int base = 0; base < NPTS; base += 64) {
    const int j = base + lane;
    const float dx = __fsub_rn(g[3 * j], nx);
    const float dy = __fsub_rn(g[3 * j + 1], ny);
    const float dz = __fsub_rn(g[3 * j + 2], nz);
    const float d2 = __fadd_rn(__fadd_rn(__fmul_rn(dx, dx), __fmul_rn(dy, dy)),
                               __fmul_rn(dz, dz));
    const bool hit = d2 <= r2;
    const unsigned long long m = __ballot(hit);
    const int pos = cnt + __popcll(m & ((1ull << lane) - 1ull));
    if (hit && pos < NSAMPLE) sidx[wv][pos] = j;
    cnt += __popcll(m);
    if (cnt >= NSAMPLE) break;  // wave-uniform
  }
  __syncthreads();
  const int capped = cnt < NSAMPLE ? cnt : NSAMPLE;
  if (lane < NSAMPLE) {
    const int v = sidx[wv][lane < capped ? lane : 0];  // pad with first hit
    ballidx[(size_t)q * NSAMPLE + lane] = v;
    out_idx[(size_t)q * NSAMPLE + lane] = (float)v;
  }
}

// ---------------------------------------------------------------------------
// P1[b,j,d] = sum_c points[b,j,c] * W0[3+c, d]  (points-part of layer 1).
// ---------------------------------------------------------------------------
__global__ __launch_bounds__(256) void p1_kernel(const float* __restrict__ pts,
                                                 const float* __restrict__ W0,
                                                 float* __restrict__ P1) {
  __shared__ float sw[4096];
  const int t = threadIdx.x;
  {
    const float4* w4 = (const float4*)(W0 + 192);
    float4* s4 = (float4*)sw;
#pragma unroll
    for (int m = 0; m < 4; ++m) s4[t + 256 * m] = w4[t + 256 * m];
  }
  __syncthreads();
  const size_t r = (size_t)blockIdx.x * 256 + t;
  const float* prow = pts + r * 64;
  float acc[64];
#pragma unroll
  for (int d = 0; d < 64; ++d) acc[d] = 0.0f;
#pragma unroll
  for (int cq = 0; cq < 16; ++cq) {
    const float4 p4 = *(const float4*)(prow + cq * 4);
    const float pv[4] = {p4.x, p4.y, p4.z, p4.w};
#pragma unroll
    for (int u = 0; u < 4; ++u) {
      const int c = cq * 4 + u;
#pragma unroll
      for (int d4 = 0; d4 < 16; ++d4) {
        const float4 w = *(const float4*)(&sw[c * 64 + d4 * 4]);
        acc[d4 * 4 + 0] = fmaf(pv[u], w.x, acc[d4 * 4 + 0]);
        acc[d4 * 4 + 1] = fmaf(pv[u], w.y, acc[d4 * 4 + 1]);
        acc[d4 * 4 + 2] = fmaf(pv[u], w.z, acc[d4 * 4 + 2]);
        acc[d4 * 4 + 3] = fmaf(pv[u], w.w, acc[d4 * 4 + 3]);
      }
    }
  }
  float* o = P1 + r * 64;
#pragma unroll
  for (int d4 = 0; d4 < 16; ++d4)
    *(float4*)(o + d4 * 4) =
        make_float4(acc[d4 * 4], acc[d4 * 4 + 1], acc[d4 * 4 + 2], acc[d4 * 4 + 3]);
}

// ---------------------------------------------------------------------------
// Fused group + MLP + maxpool. Weights/biases read directly from global with
// wave-uniform addresses (scalar-load path, L2-hot). Thread = (query, sample).
// ---------------------------------------------------------------------------
__global__ __launch_bounds__(256) void mlp_kernel(
    const float* __restrict__ xyz, const float* __restrict__ new_xyz,
    const int* __restrict__ ballidx, const float* __restrict__ P1,
    const float* __restrict__ W0, const float* __restrict__ b0,
    const float* __restrict__ W1, const float* __restrict__ b1,
    const float* __restrict__ W2, const float* __restrict__ b2,
    float* __restrict__ out_np) {
  const int t = threadIdx.x;
  const int item = blockIdx.x * 256 + t;
  const int k = item & 31;
  const int q = item >> 5;
  const int b = q >> 10;
  const int idx = ballidx[(size_t)q * 32 + k];
  const float nx = new_xyz[(size_t)q * 3];
  const float ny = new_xyz[(size_t)q * 3 + 1];
  const float nz = new_xyz[(size_t)q * 3 + 2];
  const float* p = xyz + ((size_t)b * NPTS + idx) * 3;
  const float dx = p[0] - nx, dy = p[1] - ny, dz = p[2] - nz;

  float h1[64];
  const float* p1r = P1 + ((size_t)b * NPTS + idx) * 64;
#pragma unroll
  for (int d4 = 0; d4 < 16; ++d4) {
    const float4 pv = *(const float4*)(p1r + d4 * 4);
    const float pe[4] = {pv.x, pv.y, pv.z, pv.w};
#pragma unroll
    for (int u = 0; u < 4; ++u) {
      const int d = d4 * 4 + u;
      const float v = pe[u] + dx * W0[d] + dy * W0[64 + d] + dz * W0[128 + d] + b0[d];
      h1[d] = fmaxf(v, 0.0f);
    }
  }

  float h2[64];
#pragma unroll
  for (int j4 = 0; j4 < 16; ++j4) {
    const float4 bb = *(const float4*)(&b1[j4 * 4]);
    h2[j4 * 4 + 0] = bb.x; h2[j4 * 4 + 1] = bb.y;
    h2[j4 * 4 + 2] = bb.z; h2[j4 * 4 + 3] = bb.w;
  }
#pragma unroll
  for (int c = 0; c < 64; ++c) {
    const float hc = h1[c];
#pragma unroll
    for (int j4 = 0; j4 < 16; ++j4) {
      const float4 w = *(const float4*)(&W1[c * 64 + j4 * 4]);
      h2[j4 * 4 + 0] = fmaf(hc, w.x, h2[j4 * 4 + 0]);
      h2[j4 * 4 + 1] = fmaf(hc, w.y, h2[j4 * 4 + 1]);
      h2[j4 * 4 + 2] = fmaf(hc, w.z, h2[j4 * 4 + 2]);
      h2[j4 * 4 + 3] = fmaf(hc, w.w, h2[j4 * 4 + 3]);
    }
  }
#pragma unroll
  for (int j = 0; j < 64; ++j) h2[j] = fmaxf(h2[j], 0.0f);

  float* outq = out_np + (size_t)q * 128;
  for (int jb = 0; jb < 4; ++jb) {
    float acc[32];
#pragma unroll
    for (int j8 = 0; j8 < 8; ++j8) {
      const float4 bb = *(const float4*)(&b2[jb * 32 + j8 * 4]);
      acc[j8 * 4 + 0] = bb.x; acc[j8 * 4 + 1] = bb.y;
      acc[j8 * 4 + 2] = bb.z; acc[j8 * 4 + 3] = bb.w;
    }
#pragma unroll
    for (int c = 0; c < 64; ++c) {
      const float hc = h2[c];
#pragma unroll
      for (int j8 = 0; j8 < 8; ++j8) {
        const float4 w = *(const float4*)(&W2[c * 128 + jb * 32 + j8 * 4]);
        acc[j8 * 4 + 0] = fmaf(hc, w.x, acc[j8 * 4 + 0]);
        acc[j8 * 4 + 1] = fmaf(hc, w.y, acc[j8 * 4 + 1]);
        acc[j8 * 4 + 2] = fmaf(hc, w.z, acc[j8 * 4 + 2]);
        acc[j8 * 4 + 3] = fmaf(hc, w.w, acc[j8 * 4 + 3]);
      }
    }
#pragma unroll
    for (int j = 0; j < 32; ++j) acc[j] = fmaxf(acc[j], 0.0f);
#pragma unroll
    for (int msk = 16; msk >= 1; msk >>= 1) {
#pragma unroll
      for (int j = 0; j < 32; ++j) acc[j] = fmaxf(acc[j], __shfl_xor(acc[j], msk, 64));
    }
    if (k == 0) {
#pragma unroll
      for (int j8 = 0; j8 < 8; ++j8)
        *(float4*)(outq + jb * 32 + j8 * 4) =
            make_float4(acc[j8 * 4 + 0], acc[j8 * 4 + 1], acc[j8 * 4 + 2], acc[j8 * 4 + 3]);
    }
  }
}

extern "C" void kernel_launch(void* const* d_in, const int* in_sizes, int n_in,
                              void* d_out, int out_size, void* d_ws, size_t ws_size,
                              hipStream_t stream) {
  const float* xyz = (const float*)d_in[0];
  const float* pts = (const float*)d_in[1];
  const float* W0  = (const float*)d_in[2];
  const float* b0  = (const float*)d_in[3];
  const float* W1  = (const float*)d_in[4];
  const float* b1  = (const float*)d_in[5];
  const float* W2  = (const float*)d_in[6];
  const float* b2  = (const float*)d_in[7];

  float* out      = (float*)d_out;
  float* out_xyz  = out;                       // [16,1024,3]
  float* out_np   = out + 16 * 1024 * 3;       // [16,1024,128]
  float* out_idx  = out_np + 16 * 1024 * 128;  // [16,1024,32] as float values

  int*   ballidx = (int*)d_ws;                               // 2 MB
  float* P1      = (float*)((char*)d_ws + (2u << 20));       // 16 MB

  fps_kernel<<<NB, 512, 0, stream>>>(xyz, out_xyz);
  p1_kernel<<<256, 256, 0, stream>>>(pts, W0, P1);
  ballq_kernel<<<4096, 256, 0, stream>>>(xyz, out_xyz, ballidx, out_idx);
  mlp_kernel<<<2048, 256, 0, stream>>>(xyz, out_xyz, ballidx, P1,
                                       W0, b0, W1, b1, W2, b2, out_np);
}

// Round 5
// 993.869 us; speedup vs baseline: 2.0477x; 2.0477x over previous
//
#include <hip/hip_runtime.h>

#define NB      16
#define NPTS    4096
#define NPOINT  1024
#define NSAMPLE 32

// ---------------- DPP / swizzle / bpermute u64-key max helpers ----------------
template <int C>
__device__ __forceinline__ int dppi(int v) {
  return __builtin_amdgcn_update_dpp(0, v, C, 0xf, 0xf, true);
}

template <int C>
__device__ __forceinline__ unsigned long long dppmax_u64(unsigned long long k) {
  int lo = dppi<C>((int)(unsigned)k);
  int hi = dppi<C>((int)(k >> 32));
  unsigned long long o = ((unsigned long long)(unsigned)hi << 32) | (unsigned)lo;
  return o > k ? o : k;
}

__device__ __forceinline__ unsigned long long swzmax16_u64(unsigned long long k) {
  int lo = __builtin_amdgcn_ds_swizzle((int)(unsigned)k, 0x401F);  // lane ^= 16
  int hi = __builtin_amdgcn_ds_swizzle((int)(k >> 32), 0x401F);
  unsigned long long o = ((unsigned long long)(unsigned)hi << 32) | (unsigned)lo;
  return o > k ? o : k;
}

__device__ __forceinline__ unsigned long long bpermmax32_u64(unsigned long long k, int addr) {
  int lo = __builtin_amdgcn_ds_bpermute(addr, (int)(unsigned)k);  // lane ^= 32
  int hi = __builtin_amdgcn_ds_bpermute(addr, (int)(k >> 32));
  unsigned long long o = ((unsigned long long)(unsigned)hi << 32) | (unsigned)lo;
  return o > k ? o : k;
}

// ---------------------------------------------------------------------------
// FPS v5 = v3 + (a) NO global store inside the loop: centers buffered in LDS
// and flushed once at the end. v3's per-iter `ob[...]` store forced the
// compiler's s_waitcnt vmcnt(0) before every s_barrier => all 8 waves waited
// on an HBM store ack each iteration. (b) tree-shaped local argmax (named
// scalars only -- no arrays passed by pointer, no tuple carry: both reverted
// after v4's scratch-traffic regression).
// 512 threads (2 waves/SIMD), 8 pts/thread, exact-IEEE math, 1 barrier/iter.
// ---------------------------------------------------------------------------
__global__ __launch_bounds__(512) void fps_kernel(const float* __restrict__ xyz,
                                                  float* __restrict__ out_xyz) {
  __shared__ float lx[NPTS], ly[NPTS], lz[NPTS];
  __shared__ float scen[NPOINT * 3];
  __shared__ unsigned long long part[2][8];
  const int b = blockIdx.x, t = threadIdx.x;
  const int lane = t & 63;
  const int wid = t >> 6;
  const float* g = xyz + (size_t)b * NPTS * 3;
  for (int j = t; j < NPTS; j += 512) {
    lx[j] = g[3 * j]; ly[j] = g[3 * j + 1]; lz[j] = g[3 * j + 2];
  }
  __syncthreads();
  float px[8], py[8], pz[8], mind[8];
#pragma unroll
  for (int i = 0; i < 8; ++i) {
    const int j = t + 512 * i;
    px[i] = lx[j]; py[i] = ly[j]; pz[i] = lz[j];
    mind[i] = 1e10f;
  }
  const int baddr = ((lane ^ 32) & 63) << 2;  // bpermute byte addr, loop-invariant
  float cx = lx[0], cy = ly[0], cz = lz[0];   // far = 0 initially
  for (int it = 0; it < NPOINT; ++it) {
    if (t == 0) {  // LDS write only -- cheap lgkm drain at the barrier
      scen[3 * it] = cx; scen[3 * it + 1] = cy; scen[3 * it + 2] = cz;
    }
    // ---- update mind (exact IEEE, no fma contraction) ----
#pragma unroll
    for (int i = 0; i < 8; ++i) {
      const float dx = __fsub_rn(px[i], cx);
      const float dy = __fsub_rn(py[i], cy);
      const float dz = __fsub_rn(pz[i], cz);
      const float d2 = __fadd_rn(__fadd_rn(__fmul_rn(dx, dx), __fmul_rn(dy, dy)),
                                 __fmul_rn(dz, dz));
      mind[i] = fminf(mind[i], d2);
    }
    // ---- depth-3 tree max + parallel smallest-i encode ----
    const float m01 = fmaxf(mind[0], mind[1]), m23 = fmaxf(mind[2], mind[3]);
    const float m45 = fmaxf(mind[4], mind[5]), m67 = fmaxf(mind[6], mind[7]);
    const float m0123 = fmaxf(m01, m23), m4567 = fmaxf(m45, m67);
    const float m = fmaxf(m0123, m4567);
    const unsigned s0 = (mind[0] == m) ? 0u : 255u;
    const unsigned s1 = (mind[1] == m) ? 1u : 255u;
    const unsigned s2 = (mind[2] == m) ? 2u : 255u;
    const unsigned s3 = (mind[3] == m) ? 3u : 255u;
    const unsigned s4 = (mind[4] == m) ? 4u : 255u;
    const unsigned s5 = (mind[5] == m) ? 5u : 255u;
    const unsigned s6 = (mind[6] == m) ? 6u : 255u;
    const unsigned s7 = (mind[7] == m) ? 7u : 255u;
    const unsigned enc = min(min(min(s0, s1), min(s2, s3)),
                             min(min(s4, s5), min(s6, s7)));
    const unsigned aj = (unsigned)t + (enc << 9);  // j = t + 512*i; min i <=> min j per thread
    // ---- in-wave butterfly on u64 key (val<<32 | ~j : unique) ----
    unsigned long long key =
        ((unsigned long long)__float_as_uint(m) << 32) | (unsigned)(~aj);
    key = dppmax_u64<0xB1>(key);       // xor 1
    key = dppmax_u64<0x4E>(key);       // xor 2
    key = dppmax_u64<0x141>(key);      // half-mirror (covers 8)
    key = dppmax_u64<0x140>(key);      // mirror (covers 16)
    key = swzmax16_u64(key);           // xor 16
    key = bpermmax32_u64(key, baddr);  // xor 32 -> full-wave max
    const int buf = it & 1;
    if (lane == 0) part[buf][wid] = key;
    __syncthreads();
    // ---- final reduce over 8 partials + broadcast coord lookup ----
    unsigned long long rk = part[buf][lane & 7];
    rk = dppmax_u64<0xB1>(rk);    // xor 1
    rk = dppmax_u64<0x4E>(rk);    // xor 2
    rk = dppmax_u64<0x141>(rk);   // covers all 8
    const unsigned idx = ~(unsigned)rk;  // winner point index (block-uniform)
    cx = lx[idx]; cy = ly[idx]; cz = lz[idx];  // 3 broadcast LDS reads
  }
  __syncthreads();
  float* ob = out_xyz + (size_t)b * NPOINT * 3;
  for (int i = t; i < NPOINT * 3; i += 512) ob[i] = scen[i];
}

// ---------------------------------------------------------------------------
// Ball query: one wave per query; 64 candidates/step; ordered append via
// __ballot + prefix popcount; uniform early exit at 32 hits.
// ---------------------------------------------------------------------------
__global__ __launch_bounds__(256) void ballq_kernel(const float* __restrict__ xyz,
                                                    const float* __restrict__ new_xyz,
                                                    int* __restrict__ ballidx,
                                                    float* __restrict__ out_idx) {
  __shared__ int sidx[4][NSAMPLE];
  const int wv = threadIdx.x >> 6, lane = threadIdx.x & 63;
  const int q = blockIdx.x * 4 + wv;
  const int b = q >> 10;
  const float* g = xyz + (size_t)b * NPTS * 3;
  const float nx = new_xyz[(size_t)q * 3];
  const float ny = new_xyz[(size_t)q * 3 + 1];
  const float nz = new_xyz[(size_t)q * 3 + 2];
  const float r2 = (float)(0.2 * 0.2);  // double->f32 (NOT 0.2f*0.2f)
  int cnt = 0;
  for (int base = 0; base < NPTS; base += 64) {
    const int j = base + lane;
    const float dx = __fsub_rn(g[3 * j], nx);
    const float dy = __fsub_rn(g[3 * j + 1], ny);
    const float dz = __fsub_rn(g[3 * j + 2], nz);
    const float d2 = __fadd_rn(__fadd_rn(__fmul_rn(dx, dx), __fmul_rn(dy, dy)),
                               __fmul_rn(dz, dz));
    const bool hit = d2 <= r2;
    const unsigned long long m = __ballot(hit);
    const int pos = cnt + __popcll(m & ((1ull << lane) - 1ull));
    if (hit && pos < NSAMPLE) sidx[wv][pos] = j;
    cnt += __popcll(m);
    if (cnt >= NSAMPLE) break;  // wave-uniform
  }
  __syncthreads();
  const int capped = cnt < NSAMPLE ? cnt : NSAMPLE;
  if (lane < NSAMPLE) {
    const int v = sidx[wv][lane < capped ? lane : 0];  // pad with first hit
    ballidx[(size_t)q * NSAMPLE + lane] = v;
    out_idx[(size_t)q * NSAMPLE + lane] = (float)v;
  }
}

// ---------------------------------------------------------------------------
// P1[b,j,d] = sum_c points[b,j,c] * W0[3+c, d]  (points-part of layer 1).
// ---------------------------------------------------------------------------
__global__ __launch_bounds__(256) void p1_kernel(const float* __restrict__ pts,
                                                 const float* __restrict__ W0,
                                                 float* __restrict__ P1) {
  __shared__ float sw[4096];
  const int t = threadIdx.x;
  {
    const float4* w4 = (const float4*)(W0 + 192);
    float4* s4 = (float4*)sw;
#pragma unroll
    for (int m = 0; m < 4; ++m) s4[t + 256 * m] = w4[t + 256 * m];
  }
  __syncthreads();
  const size_t r = (size_t)blockIdx.x * 256 + t;
  const float* prow = pts + r * 64;
  float acc[64];
#pragma unroll
  for (int d = 0; d < 64; ++d) acc[d] = 0.0f;
#pragma unroll
  for (int cq = 0; cq < 16; ++cq) {
    const float4 p4 = *(const float4*)(prow + cq * 4);
    const float pv[4] = {p4.x, p4.y, p4.z, p4.w};
#pragma unroll
    for (int u = 0; u < 4; ++u) {
      const int c = cq * 4 + u;
#pragma unroll
      for (int d4 = 0; d4 < 16; ++d4) {
        const float4 w = *(const float4*)(&sw[c * 64 + d4 * 4]);
        acc[d4 * 4 + 0] = fmaf(pv[u], w.x, acc[d4 * 4 + 0]);
        acc[d4 * 4 + 1] = fmaf(pv[u], w.y, acc[d4 * 4 + 1]);
        acc[d4 * 4 + 2] = fmaf(pv[u], w.z, acc[d4 * 4 + 2]);
        acc[d4 * 4 + 3] = fmaf(pv[u], w.w, acc[d4 * 4 + 3]);
      }
    }
  }
  float* o = P1 + r * 64;
#pragma unroll
  for (int d4 = 0; d4 < 16; ++d4)
    *(float4*)(o + d4 * 4) =
        make_float4(acc[d4 * 4], acc[d4 * 4 + 1], acc[d4 * 4 + 2], acc[d4 * 4 + 3]);
}

// ---------------------------------------------------------------------------
// Fused group + MLP + maxpool. Weights/biases read directly from global with
// wave-uniform addresses (scalar-load path, L2-hot). Thread = (query, sample).
// ---------------------------------------------------------------------------
__global__ __launch_bounds__(256) void mlp_kernel(
    const float* __restrict__ xyz, const float* __restrict__ new_xyz,
    const int* __restrict__ ballidx, const float* __restrict__ P1,
    const float* __restrict__ W0, const float* __restrict__ b0,
    const float* __restrict__ W1, const float* __restrict__ b1,
    const float* __restrict__ W2, const float* __restrict__ b2,
    float* __restrict__ out_np) {
  const int t = threadIdx.x;
  const int item = blockIdx.x * 256 + t;
  const int k = item & 31;
  const int q = item >> 5;
  const int b = q >> 10;
  const int idx = ballidx[(size_t)q * 32 + k];
  const float nx = new_xyz[(size_t)q * 3];
  const float ny = new_xyz[(size_t)q * 3 + 1];
  const float nz = new_xyz[(size_t)q * 3 + 2];
  const float* p = xyz + ((size_t)b * NPTS + idx) * 3;
  const float dx = p[0] - nx, dy = p[1] - ny, dz = p[2] - nz;

  float h1[64];
  const float* p1r = P1 + ((size_t)b * NPTS + idx) * 64;
#pragma unroll
  for (int d4 = 0; d4 < 16; ++d4) {
    const float4 pv = *(const float4*)(p1r + d4 * 4);
    const float pe[4] = {pv.x, pv.y, pv.z, pv.w};
#pragma unroll
    for (int u = 0; u < 4; ++u) {
      const int d = d4 * 4 + u;
      const float v = pe[u] + dx * W0[d] + dy * W0[64 + d] + dz * W0[128 + d] + b0[d];
      h1[d] = fmaxf(v, 0.0f);
    }
  }

  float h2[64];
#pragma unroll
  for (int j4 = 0; j4 < 16; ++j4) {
    const float4 bb = *(const float4*)(&b1[j4 * 4]);
    h2[j4 * 4 + 0] = bb.x; h2[j4 * 4 + 1] = bb.y;
    h2[j4 * 4 + 2] = bb.z; h2[j4 * 4 + 3] = bb.w;
  }
#pragma unroll
  for (int c = 0; c < 64; ++c) {
    const float hc = h1[c];
#pragma unroll
    for (int j4 = 0; j4 < 16; ++j4) {
      const float4 w = *(const float4*)(&W1[c * 64 + j4 * 4]);
      h2[j4 * 4 + 0] = fmaf(hc, w.x, h2[j4 * 4 + 0]);
      h2[j4 * 4 + 1] = fmaf(hc, w.y, h2[j4 * 4 + 1]);
      h2[j4 * 4 + 2] = fmaf(hc, w.z, h2[j4 * 4 + 2]);
      h2[j4 * 4 + 3] = fmaf(hc, w.w, h2[j4 * 4 + 3]);
    }
  }
#pragma unroll
  for (int j = 0; j < 64; ++j) h2[j] = fmaxf(h2[j], 0.0f);

  float* outq = out_np + (size_t)q * 128;
  for (int jb = 0; jb < 4; ++jb) {
    float acc[32];
#pragma unroll
    for (int j8 = 0; j8 < 8; ++j8) {
      const float4 bb = *(const float4*)(&b2[jb * 32 + j8 * 4]);
      acc[j8 * 4 + 0] = bb.x; acc[j8 * 4 + 1] = bb.y;
      acc[j8 * 4 + 2] = bb.z; acc[j8 * 4 + 3] = bb.w;
    }
#pragma unroll
    for (int c = 0; c < 64; ++c) {
      const float hc = h2[c];
#pragma unroll
      for (int j8 = 0; j8 < 8; ++j8) {
        const float4 w = *(const float4*)(&W2[c * 128 + jb * 32 + j8 * 4]);
        acc[j8 * 4 + 0] = fmaf(hc, w.x, acc[j8 * 4 + 0]);
        acc[j8 * 4 + 1] = fmaf(hc, w.y, acc[j8 * 4 + 1]);
        acc[j8 * 4 + 2] = fmaf(hc, w.z, acc[j8 * 4 + 2]);
        acc[j8 * 4 + 3] = fmaf(hc, w.w, acc[j8 * 4 + 3]);
      }
    }
#pragma unroll
    for (int j = 0; j < 32; ++j) acc[j] = fmaxf(acc[j], 0.0f);
#pragma unroll
    for (int msk = 16; msk >= 1; msk >>= 1) {
#pragma unroll
      for (int j = 0; j < 32; ++j) acc[j] = fmaxf(acc[j], __shfl_xor(acc[j], msk, 64));
    }
    if (k == 0) {
#pragma unroll
      for (int j8 = 0; j8 < 8; ++j8)
        *(float4*)(outq + jb * 32 + j8 * 4) =
            make_float4(acc[j8 * 4 + 0], acc[j8 * 4 + 1], acc[j8 * 4 + 2], acc[j8 * 4 + 3]);
    }
  }
}

extern "C" void kernel_launch(void* const* d_in, const int* in_sizes, int n_in,
                              void* d_out, int out_size, void* d_ws, size_t ws_size,
                              hipStream_t stream) {
  const float* xyz = (const float*)d_in[0];
  const float* pts = (const float*)d_in[1];
  const float* W0  = (const float*)d_in[2];
  const float* b0  = (const float*)d_in[3];
  const float* W1  = (const float*)d_in[4];
  const float* b1  = (const float*)d_in[5];
  const float* W2  = (const float*)d_in[6];
  const float* b2  = (const float*)d_in[7];

  float* out      = (float*)d_out;
  float* out_xyz  = out;                       // [16,1024,3]
  float* out_np   = out + 16 * 1024 * 3;       // [16,1024,128]
  float* out_idx  = out_np + 16 * 1024 * 128;  // [16,1024,32] as float values

  int*   ballidx = (int*)d_ws;                               // 2 MB
  float* P1      = (float*)((char*)d_ws + (2u << 20));       // 16 MB

  fps_kernel<<<NB, 512, 0, stream>>>(xyz, out_xyz);
  p1_kernel<<<256, 256, 0, stream>>>(pts, W0, P1);
  ballq_kernel<<<4096, 256, 0, stream>>>(xyz, out_xyz, ballidx, out_idx);
  mlp_kernel<<<2048, 256, 0, stream>>>(xyz, out_xyz, ballidx, P1,
                                       W0, b0, W1, b1, W2, b2, out_np);
}

// Round 6
// 953.373 us; speedup vs baseline: 2.1347x; 1.0425x over previous
//
#include <hip/hip_runtime.h>

#define NB      16
#define NPTS    4096
#define NPOINT  1024
#define NSAMPLE 32

typedef float v2f __attribute__((ext_vector_type(2)));

// ---- packed f32 ops (VOP3P, exact IEEE RN per half; NOT fused) ----
__device__ __forceinline__ v2f pk_add(v2f a, v2f b) {
  v2f d;
  asm("v_pk_add_f32 %0, %1, %2" : "=v"(d) : "v"(a), "v"(b));
  return d;
}
__device__ __forceinline__ v2f pk_mul(v2f a, v2f b) {
  v2f d;
  asm("v_pk_mul_f32 %0, %1, %2" : "=v"(d) : "v"(a), "v"(b));
  return d;
}
__device__ __forceinline__ float fnegx(float x) {  // exact bit-flip negation
  return __int_as_float(__float_as_int(x) ^ 0x80000000);
}

// ---------------- DPP / swizzle u64-key max helpers ----------------
template <int C>
__device__ __forceinline__ int dppi(int v) {
  return __builtin_amdgcn_update_dpp(0, v, C, 0xf, 0xf, true);
}

template <int C>
__device__ __forceinline__ unsigned long long dppmax_u64(unsigned long long k) {
  int lo = dppi<C>((int)(unsigned)k);
  int hi = dppi<C>((int)(k >> 32));
  unsigned long long o = ((unsigned long long)(unsigned)hi << 32) | (unsigned)lo;
  return o > k ? o : k;
}

__device__ __forceinline__ unsigned long long swzmax16_u64(unsigned long long k) {
  int lo = __builtin_amdgcn_ds_swizzle((int)(unsigned)k, 0x401F);  // lane ^= 16
  int hi = __builtin_amdgcn_ds_swizzle((int)(k >> 32), 0x401F);
  unsigned long long o = ((unsigned long long)(unsigned)hi << 32) | (unsigned)lo;
  return o > k ? o : k;
}

// ---------------------------------------------------------------------------
// FPS v6 = v5 structure with issue-count cuts (FPS is VALU-issue-bound:
// 62% VALU-busy on active CUs at R5):
//  - packed v_pk_add/v_pk_mul update loop (points in float2 pairs), exact
//    IEEE: sub as add-of-negated (bit-flip), two-rounding mul+add (no fma)
//  - local argmax as 7-node u64 (val<<32|~j) max tree: pack is free pair
//    assembly (nlo loop-invariant), replaces tree-max+encode (~42 -> 21)
//  - butterfly: 4 DPP + swz^16 only (no bperm); lanes 0/32 write 2 partials
//    per wave (16 slots); post-barrier: broadcast read + 4 DPP steps
// 512 threads (2 waves/SIMD), 8 pts/thread, 1 barrier/iter, centers in LDS.
// ---------------------------------------------------------------------------
__global__ __launch_bounds__(512) void fps_kernel(const float* __restrict__ xyz,
                                                  float* __restrict__ out_xyz) {
  __shared__ float lx[NPTS], ly[NPTS], lz[NPTS];
  __shared__ float scen[NPOINT * 3];
  __shared__ unsigned long long part[2][16];
  const int b = blockIdx.x, t = threadIdx.x;
  const int lane = t & 63;
  const int wid = t >> 6;
  const float* g = xyz + (size_t)b * NPTS * 3;
  for (int j = t; j < NPTS; j += 512) {
    lx[j] = g[3 * j]; ly[j] = g[3 * j + 1]; lz[j] = g[3 * j + 2];
  }
  __syncthreads();
  // pair p holds points j = t + 512*(2p) (.x) and j + 512 (.y)
  v2f px2[4], py2[4], pz2[4], mind2[4];
  unsigned nlo[8];
#pragma unroll
  for (int p = 0; p < 4; ++p) {
    const int j0 = t + 512 * (2 * p);
    px2[p] = (v2f){lx[j0], lx[j0 + 512]};
    py2[p] = (v2f){ly[j0], ly[j0 + 512]};
    pz2[p] = (v2f){lz[j0], lz[j0 + 512]};
    mind2[p] = (v2f){1e10f, 1e10f};
    nlo[2 * p] = ~(unsigned)j0;
    nlo[2 * p + 1] = ~(unsigned)(j0 + 512);
  }
  float cx = lx[0], cy = ly[0], cz = lz[0];  // far = 0 initially
  for (int it = 0; it < NPOINT; ++it) {
    if (t == 0) {  // LDS-only write; flushed to global after the loop
      scen[3 * it] = cx; scen[3 * it + 1] = cy; scen[3 * it + 2] = cz;
    }
    const float ncx = fnegx(cx), ncy = fnegx(cy), ncz = fnegx(cz);
    const v2f ncxx = (v2f){ncx, ncx};
    const v2f ncyy = (v2f){ncy, ncy};
    const v2f nczz = (v2f){ncz, ncz};
    // ---- packed update: d2 = ((dx*dx + dy*dy) + dz*dz), two roundings ----
#pragma unroll
    for (int p = 0; p < 4; ++p) {
      const v2f dx = pk_add(px2[p], ncxx);
      const v2f dy = pk_add(py2[p], ncyy);
      const v2f dz = pk_add(pz2[p], nczz);
      const v2f xx = pk_mul(dx, dx);
      const v2f yy = pk_mul(dy, dy);
      const v2f zz = pk_mul(dz, dz);
      v2f s = pk_add(xx, yy);
      s = pk_add(s, zz);
      mind2[p].x = fminf(mind2[p].x, s.x);
      mind2[p].y = fminf(mind2[p].y, s.y);
    }
    // ---- local argmax: 7-node u64 max tree (pack = free pair assembly) ----
    unsigned long long k[8];
#pragma unroll
    for (int p = 0; p < 4; ++p) {
      k[2 * p] = ((unsigned long long)__float_as_uint(mind2[p].x) << 32) | nlo[2 * p];
      k[2 * p + 1] =
          ((unsigned long long)__float_as_uint(mind2[p].y) << 32) | nlo[2 * p + 1];
    }
#pragma unroll
    for (int s = 4; s; s >>= 1)
#pragma unroll
      for (int i = 0; i < s; ++i) k[i] = k[i] > k[i + s] ? k[i] : k[i + s];
    // ---- in-wave butterfly: 4 DPP + swz^16 -> 32-lane group max ----
    unsigned long long key = k[0];
    key = dppmax_u64<0xB1>(key);   // xor 1
    key = dppmax_u64<0x4E>(key);   // xor 2
    key = dppmax_u64<0x141>(key);  // half-mirror (covers 8)
    key = dppmax_u64<0x140>(key);  // mirror (covers 16)
    key = swzmax16_u64(key);       // xor 16 -> 32-lane uniform
    const int buf = it & 1;
    if ((lane & 31) == 0) part[buf][wid * 2 + (lane >> 5)] = key;  // 16 partials
    __syncthreads();
    // ---- final reduce over 16 partials + broadcast coord lookup ----
    unsigned long long rk = part[buf][lane & 15];
    rk = dppmax_u64<0xB1>(rk);   // xor 1
    rk = dppmax_u64<0x4E>(rk);   // xor 2
    rk = dppmax_u64<0x141>(rk);  // covers 8
    rk = dppmax_u64<0x140>(rk);  // covers 16
    const unsigned idx = ~(unsigned)rk;  // winner point index (block-uniform)
    cx = lx[idx]; cy = ly[idx]; cz = lz[idx];  // 3 broadcast LDS reads
  }
  __syncthreads();
  float* ob = out_xyz + (size_t)b * NPOINT * 3;
  for (int i = t; i < NPOINT * 3; i += 512) ob[i] = scen[i];
}

// ---------------------------------------------------------------------------
// Ball query: one wave per query; 64 candidates/step; ordered append via
// __ballot + prefix popcount; uniform early exit at 32 hits.
// ---------------------------------------------------------------------------
__global__ __launch_bounds__(256) void ballq_kernel(const float* __restrict__ xyz,
                                                    const float* __restrict__ new_xyz,
                                                    int* __restrict__ ballidx,
                                                    float* __restrict__ out_idx) {
  __shared__ int sidx[4][NSAMPLE];
  const int wv = threadIdx.x >> 6, lane = threadIdx.x & 63;
  const int q = blockIdx.x * 4 + wv;
  const int b = q >> 10;
  const float* g = xyz + (size_t)b * NPTS * 3;
  const float nx = new_xyz[(size_t)q * 3];
  const float ny = new_xyz[(size_t)q * 3 + 1];
  const float nz = new_xyz[(size_t)q * 3 + 2];
  const float r2 = (float)(0.2 * 0.2);  // double->f32 (NOT 0.2f*0.2f)
  int cnt = 0;
  for (int base = 0; base < NPTS; base += 64) {
    const int j = base + lane;
    const float dx = __fsub_rn(g[3 * j], nx);
    const float dy = __fsub_rn(g[3 * j + 1], ny);
    const float dz = __fsub_rn(g[3 * j + 2], nz);
    const float d2 = __fadd_rn(__fadd_rn(__fmul_rn(dx, dx), __fmul_rn(dy, dy)),
                               __fmul_rn(dz, dz));
    const bool hit = d2 <= r2;
    const unsigned long long m = __ballot(hit);
    const int pos = cnt + __popcll(m & ((1ull << lane) - 1ull));
    if (hit && pos < NSAMPLE) sidx[wv][pos] = j;
    cnt += __popcll(m);
    if (cnt >= NSAMPLE) break;  // wave-uniform
  }
  __syncthreads();
  const int capped = cnt < NSAMPLE ? cnt : NSAMPLE;
  if (lane < NSAMPLE) {
    const int v = sidx[wv][lane < capped ? lane : 0];  // pad with first hit
    ballidx[(size_t)q * NSAMPLE + lane] = v;
    out_idx[(size_t)q * NSAMPLE + lane] = (float)v;
  }
}

// ---------------------------------------------------------------------------
// P1[b,j,d] = sum_c points[b,j,c] * W0[3+c, d]  (points-part of layer 1).
// ---------------------------------------------------------------------------
__global__ __launch_bounds__(256) void p1_kernel(const float* __restrict__ pts,
                                                 const float* __restrict__ W0,
                                                 float* __restrict__ P1) {
  __shared__ float sw[4096];
  const int t = threadIdx.x;
  {
    const float4* w4 = (const float4*)(W0 + 192);
    float4* s4 = (float4*)sw;
#pragma unroll
    for (int m = 0; m < 4; ++m) s4[t + 256 * m] = w4[t + 256 * m];
  }
  __syncthreads();
  const size_t r = (size_t)blockIdx.x * 256 + t;
  const float* prow = pts + r * 64;
  float acc[64];
#pragma unroll
  for (int d = 0; d < 64; ++d) acc[d] = 0.0f;
#pragma unroll
  for (int cq = 0; cq < 16; ++cq) {
    const float4 p4 = *(const float4*)(prow + cq * 4);
    const float pv[4] = {p4.x, p4.y, p4.z, p4.w};
#pragma unroll
    for (int u = 0; u < 4; ++u) {
      const int c = cq * 4 + u;
#pragma unroll
      for (int d4 = 0; d4 < 16; ++d4) {
        const float4 w = *(const float4*)(&sw[c * 64 + d4 * 4]);
        acc[d4 * 4 + 0] = fmaf(pv[u], w.x, acc[d4 * 4 + 0]);
        acc[d4 * 4 + 1] = fmaf(pv[u], w.y, acc[d4 * 4 + 1]);
        acc[d4 * 4 + 2] = fmaf(pv[u], w.z, acc[d4 * 4 + 2]);
        acc[d4 * 4 + 3] = fmaf(pv[u], w.w, acc[d4 * 4 + 3]);
      }
    }
  }
  float* o = P1 + r * 64;
#pragma unroll
  for (int d4 = 0; d4 < 16; ++d4)
    *(float4*)(o + d4 * 4) =
        make_float4(acc[d4 * 4], acc[d4 * 4 + 1], acc[d4 * 4 + 2], acc[d4 * 4 + 3]);
}

// ---------------------------------------------------------------------------
// Fused group + MLP + maxpool. Weights/biases read directly from global with
// wave-uniform addresses (scalar-load path, L2-hot). Thread = (query, sample).
// ---------------------------------------------------------------------------
__global__ __launch_bounds__(256) void mlp_kernel(
    const float* __restrict__ xyz, const float* __restrict__ new_xyz,
    const int* __restrict__ ballidx, const float* __restrict__ P1,
    const float* __restrict__ W0, const float* __restrict__ b0,
    const float* __restrict__ W1, const float* __restrict__ b1,
    const float* __restrict__ W2, const float* __restrict__ b2,
    float* __restrict__ out_np) {
  const int t = threadIdx.x;
  const int item = blockIdx.x * 256 + t;
  const int k = item & 31;
  const int q = item >> 5;
  const int b = q >> 10;
  const int idx = ballidx[(size_t)q * 32 + k];
  const float nx = new_xyz[(size_t)q * 3];
  const float ny = new_xyz[(size_t)q * 3 + 1];
  const float nz = new_xyz[(size_t)q * 3 + 2];
  const float* p = xyz + ((size_t)b * NPTS + idx) * 3;
  const float dx = p[0] - nx, dy = p[1] - ny, dz = p[2] - nz;

  float h1[64];
  const float* p1r = P1 + ((size_t)b * NPTS + idx) * 64;
#pragma unroll
  for (int d4 = 0; d4 < 16; ++d4) {
    const float4 pv = *(const float4*)(p1r + d4 * 4);
    const float pe[4] = {pv.x, pv.y, pv.z, pv.w};
#pragma unroll
    for (int u = 0; u < 4; ++u) {
      const int d = d4 * 4 + u;
      const float v = pe[u] + dx * W0[d] + dy * W0[64 + d] + dz * W0[128 + d] + b0[d];
      h1[d] = fmaxf(v, 0.0f);
    }
  }

  float h2[64];
#pragma unroll
  for (int j4 = 0; j4 < 16; ++j4) {
    const float4 bb = *(const float4*)(&b1[j4 * 4]);
    h2[j4 * 4 + 0] = bb.x; h2[j4 * 4 + 1] = bb.y;
    h2[j4 * 4 + 2] = bb.z; h2[j4 * 4 + 3] = bb.w;
  }
#pragma unroll
  for (int c = 0; c < 64; ++c) {
    const float hc = h1[c];
#pragma unroll
    for (int j4 = 0; j4 < 16; ++j4) {
      const float4 w = *(const float4*)(&W1[c * 64 + j4 * 4]);
      h2[j4 * 4 + 0] = fmaf(hc, w.x, h2[j4 * 4 + 0]);
      h2[j4 * 4 + 1] = fmaf(hc, w.y, h2[j4 * 4 + 1]);
      h2[j4 * 4 + 2] = fmaf(hc, w.z, h2[j4 * 4 + 2]);
      h2[j4 * 4 + 3] = fmaf(hc, w.w, h2[j4 * 4 + 3]);
    }
  }
#pragma unroll
  for (int j = 0; j < 64; ++j) h2[j] = fmaxf(h2[j], 0.0f);

  float* outq = out_np + (size_t)q * 128;
  for (int jb = 0; jb < 4; ++jb) {
    float acc[32];
#pragma unroll
    for (int j8 = 0; j8 < 8; ++j8) {
      const float4 bb = *(const float4*)(&b2[jb * 32 + j8 * 4]);
      acc[j8 * 4 + 0] = bb.x; acc[j8 * 4 + 1] = bb.y;
      acc[j8 * 4 + 2] = bb.z; acc[j8 * 4 + 3] = bb.w;
    }
#pragma unroll
    for (int c = 0; c < 64; ++c) {
      const float hc = h2[c];
#pragma unroll
      for (int j8 = 0; j8 < 8; ++j8) {
        const float4 w = *(const float4*)(&W2[c * 128 + jb * 32 + j8 * 4]);
        acc[j8 * 4 + 0] = fmaf(hc, w.x, acc[j8 * 4 + 0]);
        acc[j8 * 4 + 1] = fmaf(hc, w.y, acc[j8 * 4 + 1]);
        acc[j8 * 4 + 2] = fmaf(hc, w.z, acc[j8 * 4 + 2]);
        acc[j8 * 4 + 3] = fmaf(hc, w.w, acc[j8 * 4 + 3]);
      }
    }
#pragma unroll
    for (int j = 0; j < 32; ++j) acc[j] = fmaxf(acc[j], 0.0f);
#pragma unroll
    for (int msk = 16; msk >= 1; msk >>= 1) {
#pragma unroll
      for (int j = 0; j < 32; ++j) acc[j] = fmaxf(acc[j], __shfl_xor(acc[j], msk, 64));
    }
    if (k == 0) {
#pragma unroll
      for (int j8 = 0; j8 < 8; ++j8)
        *(float4*)(outq + jb * 32 + j8 * 4) =
            make_float4(acc[j8 * 4 + 0], acc[j8 * 4 + 1], acc[j8 * 4 + 2], acc[j8 * 4 + 3]);
    }
  }
}

extern "C" void kernel_launch(void* const* d_in, const int* in_sizes, int n_in,
                              void* d_out, int out_size, void* d_ws, size_t ws_size,
                              hipStream_t stream) {
  const float* xyz = (const float*)d_in[0];
  const float* pts = (const float*)d_in[1];
  const float* W0  = (const float*)d_in[2];
  const float* b0  = (const float*)d_in[3];
  const float* W1  = (const float*)d_in[4];
  const float* b1  = (const float*)d_in[5];
  const float* W2  = (const float*)d_in[6];
  const float* b2  = (const float*)d_in[7];

  float* out      = (float*)d_out;
  float* out_xyz  = out;                       // [16,1024,3]
  float* out_np   = out + 16 * 1024 * 3;       // [16,1024,128]
  float* out_idx  = out_np + 16 * 1024 * 128;  // [16,1024,32] as float values

  int*   ballidx = (int*)d_ws;                               // 2 MB
  float* P1      = (float*)((char*)d_ws + (2u << 20));       // 16 MB

  fps_kernel<<<NB, 512, 0, stream>>>(xyz, out_xyz);
  p1_kernel<<<256, 256, 0, stream>>>(pts, W0, P1);
  ballq_kernel<<<4096, 256, 0, stream>>>(xyz, out_xyz, ballidx, out_idx);
  mlp_kernel<<<2048, 256, 0, stream>>>(xyz, out_xyz, ballidx, P1,
                                       W0, b0, W1, b1, W2, b2, out_np);
}